// Round 1
// baseline (925.654 us; speedup 1.0000x reference)
//
#include <hip/hip_runtime.h>
#include <math.h>

// ---------------- problem constants ----------------
#define TDIM 2048
#define BF   512          // B*F = 8*64
#define NS   66           // N = N_TAUS + 2K
#define KK   8
#define DT   0.05f
#define MOUT 50           // N_TAUS
#define NC   8            // t-chunks
#define LCH  256          // chunk length (NC*LCH == TDIM)
#define NCHAINS (NS*BF)   // 33792

// ---------------- ws layout (float offsets) ----------------
#define WS_NS    0                         // 66 floats: -s_full[n]
#define WS_PB    128                       // 17*50 banded POST: PB[k][j] = POST[j+k][j+8]
#define WS_DBL   1024                      // 2*4356 doubles for init ping-pong
#define WS_A     20480                     // NC*NCHAINS chunk A
#define WS_B     (WS_A + NC*NCHAINS)       // NC*NCHAINS chunk B
#define WS_CARRY (WS_B + NC*NCHAINS)       // NC*NCHAINS chunk-start carries

// ---------------- out layout (float offsets) ----------------
#define OUT_TIL 0
#define OUT_H   (TDIM*BF*MOUT)             // 52428800
#define OUT_F   (OUT_H + BF*NS)            // 52462592

__device__ __forceinline__ double sv_d(double c, int i) {
    // s_full[i] = K / (TSTR_MIN * c^(i-K))
    return 8.0 / (0.1 * pow(c, (double)(i - KK)));
}

// Build -s_full and banded POST on device (doubles, one block).
__global__ void k_init(float* __restrict__ ws) {
    double* d1 = (double*)(ws + WS_DBL);
    double* d2 = d1 + NS * NS;
    const int tid = threadIdx.x;           // 512 threads
    const double c = pow(1000.0, 1.0 / 49.0);   // (TSTR_MAX/TSTR_MIN)^(1/(N_TAUS-1))

    for (int idx = tid; idx < NS * NS; idx += 512) d1[idx] = 0.0;
    __syncthreads();
    if (tid < NS - 2) {                    // rows 1..64
        int i = tid + 1;
        double denom = sv_d(c, i + 1) - sv_d(c, i - 1);
        d1[i * NS + (i - 1)] = -(1.0 / c) / denom;
        d1[i * NS + i]       = (1.0 / c - c) / denom;
        d1[i * NS + (i + 1)] = c / denom;
    }
    __syncthreads();
    // D^8 by repeated squaring: d1->d2->d1->d2
    for (int r = 0; r < 3; r++) {
        double* src = (r & 1) ? d2 : d1;
        double* dst = (r & 1) ? d1 : d2;
        for (int idx = tid; idx < NS * NS; idx += 512) {
            int i = idx / NS, j = idx % NS;
            double acc = 0.0;
            for (int k = 0; k < NS; k++) acc += src[i * NS + k] * src[k * NS + j];
            dst[idx] = acc;
        }
        __syncthreads();
    }
    // POST[n,m] = D8[m][n] * tau[m] * s[m]^9 / 8!   (banded: |n-m|<=8)
    for (int idx = tid; idx < 17 * MOUT; idx += 512) {
        int k = idx / MOUT, j = idx % MOUT;
        int m = j + KK;
        int n = m - KK + k;                // in [0,65]
        double sm   = sv_d(c, m);
        double taum = 8.0 / sm;
        double post = d2[m * NS + n] * taum * pow(sm, 9.0) / 40320.0;
        ws[WS_PB + idx] = (float)post;
    }
    if (tid < NS) ws[WS_NS + tid] = (float)(-sv_d(c, tid));
}

// Phase 1: per (chain, chunk) affine transition (A, B):  F_end = A*F_start + B
__global__ __launch_bounds__(256) void k_phase1(const float* __restrict__ f,
                                                const float* __restrict__ alpha,
                                                const float* __restrict__ delta,
                                                float* __restrict__ ws) {
    const int chain = blockIdx.x * 256 + threadIdx.x;   // < 33792
    const int c  = blockIdx.y;
    const int n  = chain >> 9;
    const int bf = chain & 511;
    const float nsv = ws[WS_NS + n];
    const int base = c * LCH * BF + bf;
    const float* fp = f + base;
    const float* ap = alpha + base;
    const float* dp = delta + base;
    float A = 1.0f, Bc = 0.0f;
    for (int t = 0; t < LCH; t++) {
        float x  = fmaf(ap[t * BF], DT, dp[t * BF]);
        float bb = fp[t * BF] * DT;
        float a  = __expf(nsv * x);
        A *= a;
        Bc = fmaf(Bc, a, bb);
    }
    ws[WS_A + c * NCHAINS + chain] = A;
    ws[WS_B + c * NCHAINS + chain] = Bc;
}

// Phase 2: scan 8 chunk summaries per chain -> carries; final carry -> h = log(F_T)
__global__ __launch_bounds__(256) void k_phase2(float* __restrict__ ws,
                                                float* __restrict__ out) {
    const int chain = blockIdx.x * 256 + threadIdx.x;
    float F = 0.0f;                                     // init = exp(-inf) = 0
    for (int c = 0; c < NC; c++) {
        ws[WS_CARRY + c * NCHAINS + chain] = F;
        F = fmaf(ws[WS_A + c * NCHAINS + chain], F, ws[WS_B + c * NCHAINS + chain]);
    }
    const int n = chain >> 9, bf = chain & 511;
    out[OUT_H + bf * NS + n] = logf(F);
}

// Phase 3: wave per (bf, chunk). Lane l owns state n=l; lanes 0,1 also n=64,65.
// Per t: update states, 17-tap banded matvec via shuffles, write til_f + F_out.
__global__ __launch_bounds__(256) void k_phase3(const float* __restrict__ f,
                                                const float* __restrict__ alpha,
                                                const float* __restrict__ delta,
                                                const float* __restrict__ ws,
                                                float* __restrict__ out) {
    const int wid  = threadIdx.x >> 6;
    const int lane = threadIdx.x & 63;
    const int unit = blockIdx.x * 4 + wid;              // 4096 units
    const int c  = unit >> 9;
    const int bf = unit & 511;

    const float nsv = ws[WS_NS + lane];
    const float ns2 = ws[WS_NS + 64 + (lane & 1)];
    const int j = lane - KK;                            // output column m-8
    const bool outl = (j >= 0) && (j < MOUT);
    const int ja = outl ? j : 0;

    float pm[17];
#pragma unroll
    for (int k = 0; k < 17; k++)
        pm[k] = outl ? ws[WS_PB + k * MOUT + j] : 0.0f;

    float F  = ws[WS_CARRY + c * NCHAINS + (lane << 9) + bf];
    float F2 = ws[WS_CARRY + c * NCHAINS + ((64 + (lane & 1)) << 9) + bf];

    const int t0 = c * LCH;
    const float* fp = f + t0 * BF + bf;
    const float* ap = alpha + t0 * BF + bf;
    const float* dp = delta + t0 * BF + bf;
    float* til = out + OUT_TIL + (size_t)t0 * BF * MOUT + bf * MOUT + ja;
    float* fo  = out + OUT_F   + (size_t)t0 * BF * MOUT + bf * MOUT + ja;

    for (int t = 0; t < LCH; t++) {
        float x  = fmaf(ap[0], DT, dp[0]);
        float bb = fp[0] * DT;
        ap += BF; dp += BF; fp += BF;

        float a = __expf(nsv * x);
        F = fmaf(F, a, bb);
        float a2 = __expf(ns2 * x);
        F2 = fmaf(F2, a2, bb);

        float f2_0 = __shfl(F2, 0, 64);
        float f2_1 = __shfl(F2, 1, 64);

        float acc = pm[8] * F;
#pragma unroll
        for (int k = 0; k < 8; k++) {
            float v = __shfl_up(F, 8 - k, 64);
            acc = fmaf(pm[k], v, acc);
        }
#pragma unroll
        for (int k = 9; k < 17; k++) {
            float v = __shfl_down(F, k - 8, 64);
            int idx = lane - 8 + k;
            if (idx == 64) v = f2_0;
            else if (idx == 65) v = f2_1;
            acc = fmaf(pm[k], v, acc);
        }

        if (outl) {
            til[0] = acc;
            fo[0]  = F;
        }
        til += BF * MOUT;
        fo  += BF * MOUT;
    }
}

extern "C" void kernel_launch(void* const* d_in, const int* in_sizes, int n_in,
                              void* d_out, int out_size, void* d_ws, size_t ws_size,
                              hipStream_t stream) {
    const float* f     = (const float*)d_in[0];
    const float* alpha = (const float*)d_in[1];
    const float* delta = (const float*)d_in[2];
    float* out = (float*)d_out;
    float* ws  = (float*)d_ws;

    k_init  <<<1, 512, 0, stream>>>(ws);
    k_phase1<<<dim3(NCHAINS / 256, NC), 256, 0, stream>>>(f, alpha, delta, ws);
    k_phase2<<<NCHAINS / 256, 256, 0, stream>>>(ws, out);
    k_phase3<<<(BF * NC) / 4, 256, 0, stream>>>(f, alpha, delta, ws, out);
}

// Round 2
// 805.924 us; speedup vs baseline: 1.1486x; 1.1486x over previous
//
#include <hip/hip_runtime.h>
#include <math.h>

// ---------------- problem constants ----------------
#define TDIM 2048
#define BF   512          // B*F = 8*64
#define NS   66           // N = N_TAUS + 2K
#define KK   8
#define DT   0.05f
#define MOUT 50           // N_TAUS
#define NC   16           // t-chunks
#define LCH  128          // chunk length (NC*LCH == TDIM)
#define STEP 64           // LDS staging block

// ---------------- ws layout (float offsets) ----------------
#define WS_NS    0                         // 66 floats: -s_full[n]
#define WS_PB    128                       // 17*50 banded POST: PB[k][j] = POST[j+k][j+8]
#define WS_DBL   1024                      // 2*4356 doubles for init ping-pong
#define WS_A     20480                     // NC*BF*NS chunk A,  layout [(c*BF+bf)*NS + n]
#define WS_B     (WS_A + NC*BF*NS)
#define WS_CARRY (WS_B + NC*BF*NS)

// ---------------- out layout (float offsets) ----------------
#define OUT_TIL 0
#define OUT_H   (TDIM*BF*MOUT)             // 52428800
#define OUT_F   (OUT_H + BF*NS)            // 52462592

__device__ __forceinline__ double sv_d(double c, int i) {
    // s_full[i] = K / (TSTR_MIN * c^(i-K))
    return 8.0 / (0.1 * pow(c, (double)(i - KK)));
}

// Build -s_full and banded POST on device (doubles, one block).
__global__ void k_init(float* __restrict__ ws) {
    double* d1 = (double*)(ws + WS_DBL);
    double* d2 = d1 + NS * NS;
    const int tid = threadIdx.x;           // 512 threads
    const double c = pow(1000.0, 1.0 / 49.0);   // (TSTR_MAX/TSTR_MIN)^(1/(N_TAUS-1))

    for (int idx = tid; idx < NS * NS; idx += 512) d1[idx] = 0.0;
    __syncthreads();
    if (tid < NS - 2) {                    // rows 1..64
        int i = tid + 1;
        double denom = sv_d(c, i + 1) - sv_d(c, i - 1);
        d1[i * NS + (i - 1)] = -(1.0 / c) / denom;
        d1[i * NS + i]       = (1.0 / c - c) / denom;
        d1[i * NS + (i + 1)] = c / denom;
    }
    __syncthreads();
    // D^8 by repeated squaring: d1->d2->d1->d2
    for (int r = 0; r < 3; r++) {
        double* src = (r & 1) ? d2 : d1;
        double* dst = (r & 1) ? d1 : d2;
        for (int idx = tid; idx < NS * NS; idx += 512) {
            int i = idx / NS, j = idx % NS;
            double acc = 0.0;
            for (int k = 0; k < NS; k++) acc += src[i * NS + k] * src[k * NS + j];
            dst[idx] = acc;
        }
        __syncthreads();
    }
    // POST[n,m] = D8[m][n] * tau[m] * s[m]^9 / 8!   (banded: |n-m|<=8)
    for (int idx = tid; idx < 17 * MOUT; idx += 512) {
        int k = idx / MOUT, j = idx % MOUT;
        int m = j + KK;
        int n = m - KK + k;                // in [0,65]
        double sm   = sv_d(c, m);
        double taum = 8.0 / sm;
        double post = d2[m * NS + n] * taum * pow(sm, 9.0) / 40320.0;
        ws[WS_PB + idx] = (float)post;
    }
    if (tid < NS) ws[WS_NS + tid] = (float)(-sv_d(c, tid));
}

// Phase 1: wave per (bf, chunk). Lane l owns state n=l; lanes 0,1 also n=64,65.
// Computes affine chunk transition (A, B): F_end = A*F_start + B.
__global__ __launch_bounds__(256, 8) void k_sum(const float* __restrict__ f,
                                                const float* __restrict__ alpha,
                                                const float* __restrict__ delta,
                                                float* __restrict__ ws) {
    __shared__ float2 xs[4][STEP];
    const int wid  = threadIdx.x >> 6;
    const int lane = threadIdx.x & 63;
    const int unit = blockIdx.x * 4 + wid;              // 8192 units
    const int c  = unit >> 9;
    const int bf = unit & 511;

    const float nsv = ws[WS_NS + lane];
    const float ns2 = ws[WS_NS + 64 + (lane & 1)];

    const int t0 = c * LCH;
    const float* fp = f     + (size_t)t0 * BF + bf;
    const float* ap = alpha + (size_t)t0 * BF + bf;
    const float* dp = delta + (size_t)t0 * BF + bf;

    float A = 1.0f, Bc = 0.0f, A2 = 1.0f, B2 = 0.0f;
    for (int tb = 0; tb < LCH; tb += STEP) {
        float av = ap[(tb + lane) * BF];
        float dv = dp[(tb + lane) * BF];
        float fv = fp[(tb + lane) * BF];
        xs[wid][lane] = make_float2(fmaf(av, DT, dv), fv * DT);
#pragma unroll 8
        for (int tt = 0; tt < STEP; tt++) {
            float2 v = xs[wid][tt];                      // uniform addr -> broadcast
            float a = __expf(nsv * v.x);
            A *= a;  Bc = fmaf(Bc, a, v.y);
            float a2 = __expf(ns2 * v.x);
            A2 *= a2; B2 = fmaf(B2, a2, v.y);
        }
    }
    const int base = (c * BF + bf) * NS;
    ws[WS_A + base + lane] = A;
    ws[WS_B + base + lane] = Bc;
    if (lane < 2) {
        ws[WS_A + base + 64 + lane] = A2;
        ws[WS_B + base + 64 + lane] = B2;
    }
}

// Phase 2: scan NC chunk summaries per chain -> chunk-start carries; h = log(F_T)
__global__ __launch_bounds__(256) void k_phase2(float* __restrict__ ws,
                                                float* __restrict__ out) {
    const int idx = blockIdx.x * 256 + threadIdx.x;     // < 33792
    const int bf = idx / NS;
    const int n  = idx - bf * NS;
    float F = 0.0f;                                     // init = exp(-inf) = 0
    for (int c = 0; c < NC; c++) {
        const int base = (c * BF + bf) * NS + n;
        ws[WS_CARRY + base] = F;
        F = fmaf(ws[WS_A + base], F, ws[WS_B + base]);
    }
    out[OUT_H + bf * NS + n] = logf(F);
}

// Phase 3: wave per (bf, chunk). Lane l owns state n=l; ALL lanes redundantly
// carry F64, F65 (uniform recurrence -> no shuffles for the top states).
// Per t: update states, 17-tap banded matvec via shuffles, write til_f + F_out.
__global__ __launch_bounds__(256) void k_phase3(const float* __restrict__ f,
                                                const float* __restrict__ alpha,
                                                const float* __restrict__ delta,
                                                const float* __restrict__ ws,
                                                float* __restrict__ out) {
    __shared__ float2 xs[4][STEP];
    const int wid  = threadIdx.x >> 6;
    const int lane = threadIdx.x & 63;
    const int unit = blockIdx.x * 4 + wid;              // 8192 units
    const int c  = unit >> 9;
    const int bf = unit & 511;

    const float nsv  = ws[WS_NS + lane];
    const float ns64 = ws[WS_NS + 64];
    const float ns65 = ws[WS_NS + 65];
    const int j = lane - KK;                            // output column m-8
    const bool outl = (j >= 0) && (j < MOUT);
    const int ja = outl ? j : 0;

    float pm[17];
#pragma unroll
    for (int k = 0; k < 17; k++)
        pm[k] = outl ? ws[WS_PB + k * MOUT + j] : 0.0f;

    const int cb = (c * BF + bf) * NS;
    float F   = ws[WS_CARRY + cb + lane];
    float F64 = ws[WS_CARRY + cb + 64];
    float F65 = ws[WS_CARRY + cb + 65];

    const int t0 = c * LCH;
    const float* fp = f     + (size_t)t0 * BF + bf;
    const float* ap = alpha + (size_t)t0 * BF + bf;
    const float* dp = delta + (size_t)t0 * BF + bf;
    float* til = out + OUT_TIL + (size_t)t0 * BF * MOUT + bf * MOUT + ja;
    float* fo  = out + OUT_F   + (size_t)t0 * BF * MOUT + bf * MOUT + ja;

    for (int tb = 0; tb < LCH; tb += STEP) {
        float av = ap[(tb + lane) * BF];
        float dv = dp[(tb + lane) * BF];
        float fv = fp[(tb + lane) * BF];
        xs[wid][lane] = make_float2(fmaf(av, DT, dv), fv * DT);
#pragma unroll 4
        for (int tt = 0; tt < STEP; tt++) {
            float2 v = xs[wid][tt];                      // uniform addr -> broadcast

            float a = __expf(nsv * v.x);
            F = fmaf(F, a, v.y);
            float a64 = __expf(ns64 * v.x);
            F64 = fmaf(F64, a64, v.y);
            float a65 = __expf(ns65 * v.x);
            F65 = fmaf(F65, a65, v.y);

            float acc = pm[8] * F;
#pragma unroll
            for (int k = 0; k < 8; k++) {
                float vv = __shfl_up(F, 8 - k, 64);
                acc = fmaf(pm[k], vv, acc);
            }
#pragma unroll
            for (int k = 9; k < 17; k++) {
                float vv = __shfl_down(F, k - 8, 64);
                int idxn = lane - 8 + k;
                if (idxn == 64) vv = F64;
                else if (idxn == 65) vv = F65;
                acc = fmaf(pm[k], vv, acc);
            }

            if (outl) {
                til[0] = acc;
                fo[0]  = F;
            }
            til += BF * MOUT;
            fo  += BF * MOUT;
        }
    }
}

extern "C" void kernel_launch(void* const* d_in, const int* in_sizes, int n_in,
                              void* d_out, int out_size, void* d_ws, size_t ws_size,
                              hipStream_t stream) {
    const float* f     = (const float*)d_in[0];
    const float* alpha = (const float*)d_in[1];
    const float* delta = (const float*)d_in[2];
    float* out = (float*)d_out;
    float* ws  = (float*)d_ws;

    k_init  <<<1, 512, 0, stream>>>(ws);
    k_sum   <<<(BF * NC) / 4, 256, 0, stream>>>(f, alpha, delta, ws);
    k_phase2<<<(BF * NS) / 256, 256, 0, stream>>>(ws, out);
    k_phase3<<<(BF * NC) / 4, 256, 0, stream>>>(f, alpha, delta, ws, out);
}

// Round 9
// 726.189 us; speedup vs baseline: 1.2747x; 1.1098x over previous
//
#include <hip/hip_runtime.h>
#include <math.h>

// ---------------- problem constants ----------------
#define TDIM 2048
#define BF   512          // B*F = 8*64
#define NS   66           // N = N_TAUS + 2K
#define NS2  (NS*NS)
#define KK   8
#define DT   0.05f
#define MOUT 50           // N_TAUS
#define NC   16           // t-chunks
#define LCH  128          // chunk length (NC*LCH == TDIM)
#define STEP 64           // LDS staging block

// ---------------- ws layout (float offsets) ----------------
#define WS_NS    0                         // 66 floats: -s_full[n] * log2(e)
#define WS_PB    128                       // 17*50 banded POST: PB[k][j] = POST[j+k][j+8]
#define WS_A     20480                     // NC*BF*NS chunk A,  layout [(c*BF+bf)*NS + n]
#define WS_B     (WS_A + NC*BF*NS)
#define WS_CARRY (WS_B + NC*BF*NS)

// ---------------- out layout (float offsets) ----------------
#define OUT_TIL 0
#define OUT_H   (TDIM*BF*MOUT)             // 52428800
#define OUT_F   (OUT_H + BF*NS)            // 52462592

// Build -s_full*log2e and banded POST on device. Single block, all in LDS.
__global__ __launch_bounds__(512) void k_init(float* __restrict__ ws) {
    __shared__ double sd[NS2];             // 34.8 KB, in-place squared matrix
    __shared__ double sv[NS];              // s_full
    const int tid = threadIdx.x;
    const double c = pow(1000.0, 1.0 / 49.0);   // (TSTR_MAX/TSTR_MIN)^(1/(N_TAUS-1))

    if (tid < NS) sv[tid] = 8.0 / (0.1 * pow(c, (double)(tid - KK)));
    for (int idx = tid; idx < NS2; idx += 512) sd[idx] = 0.0;
    __syncthreads();
    if (tid >= 1 && tid < NS - 1) {        // rows 1..64 of tridiagonal D
        const int i = tid;
        double denom = sv[i + 1] - sv[i - 1];
        sd[i * NS + (i - 1)] = -(1.0 / c) / denom;
        sd[i * NS + i]       = (1.0 / c - c) / denom;
        sd[i * NS + (i + 1)] = c / denom;
    }
    __syncthreads();
    // D^8 by 3 in-place squarings (reg-staged)
    for (int r = 0; r < 3; r++) {
        double acc[9];
#pragma unroll
        for (int u = 0; u < 9; u++) {
            const int idx = tid + u * 512;
            double a = 0.0;
            if (idx < NS2) {
                const int i = idx / NS, j = idx - i * NS;
                const double* Ri = sd + i * NS;
#pragma unroll 6
                for (int k = 0; k < NS; k++) a += Ri[k] * sd[k * NS + j];
            }
            acc[u] = a;
        }
        __syncthreads();
#pragma unroll
        for (int u = 0; u < 9; u++) {
            const int idx = tid + u * 512;
            if (idx < NS2) sd[idx] = acc[u];
        }
        __syncthreads();
    }
    // POST[n,m] = D8[m][n] * tau[m] * s[m]^9 / 8!   (banded: |n-m|<=8)
    for (int idx = tid; idx < 17 * MOUT; idx += 512) {
        const int k = idx / MOUT, j = idx - k * MOUT;
        const int m = j + KK;
        const int n = m - KK + k;          // in [0,65]
        const double smv = sv[m];
        double post = sd[m * NS + n] * (8.0 / smv) * pow(smv, 9.0) / 40320.0;
        ws[WS_PB + idx] = (float)post;
    }
    if (tid < NS) ws[WS_NS + tid] = (float)(-sv[tid] * 1.4426950408889634);
}

// Phase 1: wave per (bf, chunk). Lane l owns state n=l; lanes 0,1 also 64,65.
// Computes affine chunk transition (A, B): F_end = A*F_start + B.
__global__ __launch_bounds__(256, 8) void k_sum(const float* __restrict__ f,
                                                const float* __restrict__ alpha,
                                                const float* __restrict__ delta,
                                                float* __restrict__ ws) {
    __shared__ float2 xs[4][STEP];
    const int wid  = threadIdx.x >> 6;
    const int lane = threadIdx.x & 63;
    const int unit = blockIdx.x * 4 + wid;              // 8192 units
    const int c  = unit >> 9;
    const int bf = unit & 511;

    const float nsv = ws[WS_NS + lane];
    const float ns2 = ws[WS_NS + 64 + (lane & 1)];

    const int t0 = c * LCH;
    const float* fp = f     + (size_t)t0 * BF + bf;
    const float* ap = alpha + (size_t)t0 * BF + bf;
    const float* dp = delta + (size_t)t0 * BF + bf;

    float A = 1.0f, Bc = 0.0f, A2 = 1.0f, B2 = 0.0f;
    for (int tb = 0; tb < LCH; tb += STEP) {
        float av = ap[(tb + lane) * BF];
        float dv = dp[(tb + lane) * BF];
        float fv = fp[(tb + lane) * BF];
        xs[wid][lane] = make_float2(fmaf(av, DT, dv), fv * DT);
#pragma unroll 8
        for (int tt = 0; tt < STEP; tt++) {
            float2 v = xs[wid][tt];                      // uniform addr -> broadcast
            float a = exp2f(nsv * v.x);
            A *= a;  Bc = fmaf(Bc, a, v.y);
            float a2 = exp2f(ns2 * v.x);
            A2 *= a2; B2 = fmaf(B2, a2, v.y);
        }
    }
    const int base = (c * BF + bf) * NS;
    ws[WS_A + base + lane] = A;
    ws[WS_B + base + lane] = Bc;
    if (lane < 2) {
        ws[WS_A + base + 64 + lane] = A2;
        ws[WS_B + base + 64 + lane] = B2;
    }
}

// Phase 2: scan NC chunk summaries per chain -> chunk-start carries; h = log(F_T)
__global__ __launch_bounds__(256) void k_phase2(float* __restrict__ ws,
                                                float* __restrict__ out) {
    const int idx = blockIdx.x * 256 + threadIdx.x;     // < 33792
    const int bf = idx / NS;
    const int n  = idx - bf * NS;
    float F = 0.0f;                                     // init = exp(-inf) = 0
    for (int c = 0; c < NC; c++) {
        const int base = (c * BF + bf) * NS + n;
        ws[WS_CARRY + base] = F;
        F = fmaf(ws[WS_A + base], F, ws[WS_B + base]);
    }
    out[OUT_H + bf * NS + n] = logf(F);
}

// Phase 3: wave per (bf, chunk). Lane l owns state n=l; lanes 0,1 own 64,65
// (broadcast via shuffle). Per t: state update, 17-tap banded matvec via
// shuffles, write til_f + F_out with 32-bit offsets.
__global__ __launch_bounds__(256, 8) void k_phase3(const float* __restrict__ f,
                                                   const float* __restrict__ alpha,
                                                   const float* __restrict__ delta,
                                                   const float* __restrict__ ws,
                                                   float* __restrict__ out) {
    __shared__ float2 xs[4][STEP];
    const int wid  = threadIdx.x >> 6;
    const int lane = threadIdx.x & 63;
    const int unit = blockIdx.x * 4 + wid;              // 8192 units
    const int c  = unit >> 9;
    const int bf = unit & 511;

    const float nsv = ws[WS_NS + lane];
    const float ns2 = ws[WS_NS + 64 + (lane & 1)];
    const int j = lane - KK;                            // output column m-8
    const bool outl = (j >= 0) && (j < MOUT);
    const int ja = outl ? j : 0;

    float pm[17];
#pragma unroll
    for (int k = 0; k < 17; k++)
        pm[k] = outl ? ws[WS_PB + k * MOUT + j] : 0.0f;

    const int cb = (c * BF + bf) * NS;
    float F  = ws[WS_CARRY + cb + lane];
    float F2 = ws[WS_CARRY + cb + 64 + (lane & 1)];

    const int t0 = c * LCH;
    const float* fp = f     + (size_t)t0 * BF + bf;
    const float* ap = alpha + (size_t)t0 * BF + bf;
    const float* dp = delta + (size_t)t0 * BF + bf;
    unsigned off_til = (unsigned)(OUT_TIL + t0 * BF * MOUT + bf * MOUT + ja);
    unsigned off_fo  = (unsigned)(OUT_F   + t0 * BF * MOUT + bf * MOUT + ja);

    for (int tb = 0; tb < LCH; tb += STEP) {
        float av = ap[(tb + lane) * BF];
        float dv = dp[(tb + lane) * BF];
        float fv = fp[(tb + lane) * BF];
        xs[wid][lane] = make_float2(fmaf(av, DT, dv), fv * DT);
#pragma unroll 8
        for (int tt = 0; tt < STEP; tt++) {
            float2 v = xs[wid][tt];                      // uniform addr -> broadcast

            float a = exp2f(nsv * v.x);
            F = fmaf(F, a, v.y);
            float a2 = exp2f(ns2 * v.x);
            F2 = fmaf(F2, a2, v.y);

            float f64 = __shfl(F2, 0, 64);
            float f65 = __shfl(F2, 1, 64);

            float acc = pm[8] * F;
#pragma unroll
            for (int k = 0; k < 8; k++) {
                float vv = __shfl_up(F, 8 - k, 64);
                acc = fmaf(pm[k], vv, acc);
            }
#pragma unroll
            for (int k = 9; k < 17; k++) {
                float vv = __shfl_down(F, k - 8, 64);
                int idxn = lane - 8 + k;
                if (idxn == 64) vv = f64;
                else if (idxn == 65) vv = f65;
                acc = fmaf(pm[k], vv, acc);
            }

            if (outl) {
                out[off_til] = acc;
                out[off_fo]  = F;
            }
            off_til += BF * MOUT;
            off_fo  += BF * MOUT;
        }
    }
}

extern "C" void kernel_launch(void* const* d_in, const int* in_sizes, int n_in,
                              void* d_out, int out_size, void* d_ws, size_t ws_size,
                              hipStream_t stream) {
    const float* f     = (const float*)d_in[0];
    const float* alpha = (const float*)d_in[1];
    const float* delta = (const float*)d_in[2];
    float* out = (float*)d_out;
    float* ws  = (float*)d_ws;

    k_init  <<<1, 512, 0, stream>>>(ws);
    k_sum   <<<(BF * NC) / 4, 256, 0, stream>>>(f, alpha, delta, ws);
    k_phase2<<<(BF * NS) / 256, 256, 0, stream>>>(ws, out);
    k_phase3<<<(BF * NC) / 4, 256, 0, stream>>>(f, alpha, delta, ws, out);
}